// Round 5
// baseline (506.983 us; speedup 1.0000x reference)
//
#include <hip/hip_runtime.h>
#include <stdint.h>

// Problem: N=2048, F=64, S=512, D=512
//   gi[n,f,g] = sum_s x[n,f,s] * W_ih[f,g,s]   (+ b_ih)
//   r=sig(gi_r+b_hr); z=sig(gi_z+b_hz); n=tanh(gi_n + r*b_hn); h=(1-z)*n
//
// R5: prepasses (unchanged) emit bf16 LDS-image tiles, swizzle baked in.
//     GEMM rewritten: BM=256, BD=64(x3 gates), BK=64, 512 thr (8 waves 4Mx2D),
//     double-buffered LDS (112KB), stage-2-ahead via global_load_lds,
//     counted s_waitcnt vmcnt(7) (T4 - never drain to 0 mid-loop),
//     raw s_barrier, setprio around MFMA clusters (T5).

#define NN 2048
#define FF 64
#define SS 512
#define DD 512
#define BM 256
#define BD 64
#define BK 64
#define NKT 8

#define A_SLAB 16384   // 128 rows x 64 k x 2B (prepass granularity)
#define B_SLAB 24576   // 3 gates x 64 rows x 64 k x 2B
#define XT_BYTES ((long)64 * 16 * 8 * A_SLAB)   // 134217728
#define WT_BYTES ((long)64 * 8 * 8 * B_SLAB)    // 100663296
#define BUF_STRIDE 57344   // 32KB A + 24KB B per K-tile buffer

typedef float f32x4 __attribute__((ext_vector_type(4)));
typedef __bf16 bf16x8 __attribute__((ext_vector_type(8)));
typedef unsigned short ushort8 __attribute__((ext_vector_type(8)));
typedef unsigned int uint32x4 __attribute__((ext_vector_type(4)));

#define AS1 __attribute__((address_space(1)))
#define AS3 __attribute__((address_space(3)))

__device__ __forceinline__ void gload16(const void* gsrc, void* ldst) {
    __builtin_amdgcn_global_load_lds(
        (const AS1 unsigned int*)(uintptr_t)gsrc,
        (AS3 unsigned int*)(unsigned int)(uintptr_t)ldst,
        16, 0, 0);
}

__device__ __forceinline__ ushort8 cvt8(const f32x4 a, const f32x4 b) {
    ushort8 r;
    r[0] = __builtin_bit_cast(unsigned short, (__bf16)a[0]);
    r[1] = __builtin_bit_cast(unsigned short, (__bf16)a[1]);
    r[2] = __builtin_bit_cast(unsigned short, (__bf16)a[2]);
    r[3] = __builtin_bit_cast(unsigned short, (__bf16)a[3]);
    r[4] = __builtin_bit_cast(unsigned short, (__bf16)b[0]);
    r[5] = __builtin_bit_cast(unsigned short, (__bf16)b[1]);
    r[6] = __builtin_bit_cast(unsigned short, (__bf16)b[2]);
    r[7] = __builtin_bit_cast(unsigned short, (__bf16)b[3]);
    return r;
}

__device__ __forceinline__ float fast_sigmoid(float v) {
    return 1.0f / (1.0f + __expf(-v));
}
__device__ __forceinline__ float fast_tanh(float v) {
    return 1.0f - 2.0f / (__expf(2.0f * v) + 1.0f);
}

// ---------------- prepass: x -> bf16 LDS-image tiles (unchanged) ------------
extern "C" __global__ __launch_bounds__(256)
void prep_x(const float* __restrict__ x, ushort8* __restrict__ xT) {
    const int b  = blockIdx.x;            // 8192
    const int f  = b >> 7;
    const int mt = (b >> 3) & 15;         // 128-row slab index
    const int kt = b & 7;
    const int t  = threadIdx.x;
    const long slab = (long)b * 1024;
#pragma unroll
    for (int p = 0; p < 4; ++p) {
        int q = p * 256 + t;
        int r = q >> 3;
        int s = (q & 7) ^ (r & 7);
        const f32x4* src = (const f32x4*)(x + ((long)(mt * 128 + r) * FF + f) * SS
                                          + kt * BK + s * 8);
        xT[slab + q] = cvt8(src[0], src[1]);
    }
}

extern "C" __global__ __launch_bounds__(256)
void prep_w(const float* __restrict__ W, ushort8* __restrict__ wT) {
    const int b  = blockIdx.x;            // 4096
    const int f  = b >> 6;
    const int dt = (b >> 3) & 7;
    const int kt = b & 7;
    const int t  = threadIdx.x;
    const long slab = (long)b * 1536;
#pragma unroll
    for (int p = 0; p < 6; ++p) {
        int q  = p * 256 + t;
        int g  = q >> 9;
        int rr = (q >> 3) & 63;
        int s  = (q & 7) ^ (rr & 7);
        const f32x4* src = (const f32x4*)(W + ((long)f * 1536 + g * DD + dt * BD + rr) * SS
                                          + kt * BK + s * 8);
        wT[slab + q] = cvt8(src[0], src[1]);
    }
}

// ---------------- main GEMM + fused gates (dbuf + counted vmcnt) ------------
extern "C" __global__ __launch_bounds__(512, 2)
void gru_gemm(const unsigned char* __restrict__ xT, const unsigned char* __restrict__ wT,
              const float* __restrict__ b_ih, const float* __restrict__ b_hh,
              float* __restrict__ out)
{
    // 2 buffers x (A [256][64]bf16 = 32KB, B [3][64][64]bf16 = 24KB) = 112KB
    __shared__ __align__(16) unsigned char lds[2 * BUF_STRIDE];

    const int t     = threadIdx.x;        // 0..511
    const int lane  = t & 63;
    const int wid   = t >> 6;             // 0..7
    const int wm    = wid >> 1;           // 0..3 (64-row band)
    const int wd    = wid & 1;            // 0..1 (32-col band per gate)
    const int lrow  = lane & 15;
    const int khalf = lane >> 4;

    // T1 XCD mapping: each XCD owns 8 consecutive f; d-tile innermost
    const int bid  = blockIdx.x;          // 0..4095
    const int xcd  = bid & 7;
    const int lid  = bid >> 3;            // 0..511
    const int work = xcd * 512 + lid;
    const int f    = work >> 6;           // 0..63
    const int rem  = work & 63;
    const int mt   = rem >> 3;            // 0..7 (256-row tiles)
    const int dt   = rem & 7;             // 0..7
    const int n0   = mt * BM;
    const int d0   = dt * BD;

    // image bases (A needs two 128-row slabs per 256-row tile)
    const unsigned char* aS0 = xT + (long)((f * 16 + mt * 2) * 8) * A_SLAB;
    const unsigned char* aS1 = xT + (long)((f * 16 + mt * 2 + 1) * 8) * A_SLAB;
    const unsigned char* bS  = wT + (long)((f * 8 + dt) * 8) * B_SLAB;

#define STAGE(KT)                                                              \
    do {                                                                       \
        unsigned char* dst = lds + ((KT) & 1) * BUF_STRIDE;                    \
        gload16(aS0 + (long)(KT) * A_SLAB + (0 * 512 + t) * 16,                \
                dst + (0 * 512 + t) * 16);                                     \
        gload16(aS0 + (long)(KT) * A_SLAB + (1 * 512 + t) * 16,                \
                dst + (1 * 512 + t) * 16);                                     \
        gload16(aS1 + (long)(KT) * A_SLAB + (0 * 512 + t) * 16,                \
                dst + 16384 + (0 * 512 + t) * 16);                             \
        gload16(aS1 + (long)(KT) * A_SLAB + (1 * 512 + t) * 16,                \
                dst + 16384 + (1 * 512 + t) * 16);                             \
        gload16(bS + (long)(KT) * B_SLAB + (0 * 512 + t) * 16,                 \
                dst + 32768 + (0 * 512 + t) * 16);                             \
        gload16(bS + (long)(KT) * B_SLAB + (1 * 512 + t) * 16,                 \
                dst + 32768 + (1 * 512 + t) * 16);                             \
        gload16(bS + (long)(KT) * B_SLAB + (2 * 512 + t) * 16,                 \
                dst + 32768 + (2 * 512 + t) * 16);                             \
    } while (0)

    f32x4 acc[3][4][2];
#pragma unroll
    for (int g = 0; g < 3; ++g)
#pragma unroll
        for (int i = 0; i < 4; ++i)
#pragma unroll
            for (int j = 0; j < 2; ++j)
                acc[g][i][j] = (f32x4){0.f, 0.f, 0.f, 0.f};

    // prologue: 2 tiles in flight (14 loads/thread)
    STAGE(0);
    STAGE(1);

#pragma unroll
    for (int kt = 0; kt < NKT; ++kt) {
        // retire tile kt's 7 loads; keep tile kt+1's in flight (T4)
        if (kt < NKT - 1)
            asm volatile("s_waitcnt vmcnt(7)" ::: "memory");
        else
            asm volatile("s_waitcnt vmcnt(0)" ::: "memory");
        __builtin_amdgcn_s_barrier();   // all waves: tile kt visible

        const unsigned char* buf = lds + (kt & 1) * BUF_STRIDE;
#pragma unroll
        for (int kb = 0; kb < 2; ++kb) {
            bf16x8 af[4];
#pragma unroll
            for (int i = 0; i < 4; ++i) {
                int row = wm * 64 + i * 16 + lrow;
                int off = row * 128 + ((kb * 64 + khalf * 16) ^ ((row & 7) << 4));
                af[i] = __builtin_bit_cast(bf16x8, *(const uint32x4*)(buf + off));
            }
            bf16x8 bfr[3][2];
#pragma unroll
            for (int g = 0; g < 3; ++g)
#pragma unroll
                for (int j = 0; j < 2; ++j) {
                    int dr  = wd * 32 + j * 16 + lrow;
                    int off = 32768 + g * 8192 + dr * 128 +
                              ((kb * 64 + khalf * 16) ^ ((dr & 7) << 4));
                    bfr[g][j] = __builtin_bit_cast(bf16x8, *(const uint32x4*)(buf + off));
                }
            __builtin_amdgcn_s_setprio(1);
#pragma unroll
            for (int g = 0; g < 3; ++g)
#pragma unroll
                for (int i = 0; i < 4; ++i)
#pragma unroll
                    for (int j = 0; j < 2; ++j)
                        acc[g][i][j] = __builtin_amdgcn_mfma_f32_16x16x32_bf16(
                            af[i], bfr[g][j], acc[g][i][j], 0, 0, 0);
            __builtin_amdgcn_s_setprio(0);
        }

        __builtin_amdgcn_s_barrier();   // all waves done reading buf[kt&1]
        asm volatile("" ::: "memory");  // keep stage writes below the barrier
        if (kt + 2 < NKT)
            STAGE(kt + 2);              // overwrite freed buffer; lands during kt+1
    }

    // fused gate epilogue
    const long bBase = (long)f * (3 * DD);
#pragma unroll
    for (int j = 0; j < 2; ++j) {
        int d = d0 + wd * 32 + j * 16 + lrow;
        float bihr = b_ih[bBase + d];
        float bihz = b_ih[bBase + DD + d];
        float bihn = b_ih[bBase + 2 * DD + d];
        float bhr  = b_hh[bBase + d];
        float bhz  = b_hh[bBase + DD + d];
        float bhn  = b_hh[bBase + 2 * DD + d];
#pragma unroll
        for (int i = 0; i < 4; ++i) {
#pragma unroll
            for (int q = 0; q < 4; ++q) {
                int row = wm * 64 + i * 16 + khalf * 4 + q;
                float gr = acc[0][i][j][q] + bihr + bhr;
                float gz = acc[1][i][j][q] + bihz + bhz;
                float gy = acc[2][i][j][q] + bihn;
                float r  = fast_sigmoid(gr);
                float z  = fast_sigmoid(gz);
                float nv = fast_tanh(gy + r * bhn);
                long oi  = ((long)(n0 + row) * FF + f) * DD + d;
                out[oi]  = (1.0f - z) * nv;
            }
        }
    }
#undef STAGE
}

// ---------------- fallback (R3 kernel) if ws too small ----------------
extern "C" __global__ __launch_bounds__(256, 3)
void gru_fused_fb(const float* __restrict__ x, const float* __restrict__ W,
                  const float* __restrict__ b_ih, const float* __restrict__ b_hh,
                  float* __restrict__ out)
{
    __shared__ __align__(16) unsigned char lds[28672];
    const int t     = threadIdx.x;
    const int lane  = t & 63;
    const int wid   = t >> 6;
    const int wm    = wid >> 1;
    const int wd    = wid & 1;
    const int lrow  = lane & 15;
    const int khalf = lane >> 4;
    const int bid  = blockIdx.x;
    const int xcd  = bid & 7;
    const int lid  = bid >> 3;
    const int work = xcd * 2048 + lid;
    const int f    = work >> 8;
    const int rem  = work & 255;
    const int n0   = (rem >> 4) * 128;
    const int d0   = (rem & 15) * 32;
    const int colSeg = t & 7;
    const int rBase  = t >> 3;
    const float* aPtr[4]; int aOff[4];
#pragma unroll
    for (int p = 0; p < 4; ++p) {
        int row = rBase + 32 * p;
        aPtr[p] = x + ((long)(n0 + row) * FF + f) * SS + colSeg * 8;
        aOff[p] = row * 128 + ((colSeg * 16) ^ ((row & 7) << 4));
    }
    const float* bPtr[3]; int bOff[3];
#pragma unroll
    for (int p = 0; p < 3; ++p) {
        int ra = rBase + 32 * p;
        int gate = ra >> 5, dr = ra & 31;
        bPtr[p] = W + ((long)f * 1536 + gate * DD + d0 + dr) * SS + colSeg * 8;
        bOff[p] = 16384 + gate * 4096 + dr * 128 + ((colSeg * 16) ^ ((dr & 7) << 4));
    }
    f32x4 acc[3][4];
#pragma unroll
    for (int g = 0; g < 3; ++g)
#pragma unroll
        for (int i = 0; i < 4; ++i) acc[g][i] = (f32x4){0.f, 0.f, 0.f, 0.f};
    f32x4 va[4][2], vb[3][2];
#pragma unroll
    for (int p = 0; p < 4; ++p) { const f32x4* g = (const f32x4*)aPtr[p]; va[p][0] = g[0]; va[p][1] = g[1]; }
#pragma unroll
    for (int p = 0; p < 3; ++p) { const f32x4* g = (const f32x4*)bPtr[p]; vb[p][0] = g[0]; vb[p][1] = g[1]; }
    for (int kt = 0; kt < 8; ++kt) {
        __syncthreads();
#pragma unroll
        for (int p = 0; p < 4; ++p) *(ushort8*)(lds + aOff[p]) = cvt8(va[p][0], va[p][1]);
#pragma unroll
        for (int p = 0; p < 3; ++p) *(ushort8*)(lds + bOff[p]) = cvt8(vb[p][0], vb[p][1]);
        __syncthreads();
        if (kt + 1 < 8) {
            const long koff = (long)(kt + 1) * BK;
#pragma unroll
            for (int p = 0; p < 4; ++p) { const f32x4* g = (const f32x4*)(aPtr[p] + koff); va[p][0] = g[0]; va[p][1] = g[1]; }
#pragma unroll
            for (int p = 0; p < 3; ++p) { const f32x4* g = (const f32x4*)(bPtr[p] + koff); vb[p][0] = g[0]; vb[p][1] = g[1]; }
        }
#pragma unroll
        for (int kb = 0; kb < 2; ++kb) {
            bf16x8 af[4];
#pragma unroll
            for (int i = 0; i < 4; ++i) {
                int row = wm * 64 + i * 16 + lrow;
                int off = row * 128 + ((kb * 64 + khalf * 16) ^ ((row & 7) << 4));
                af[i] = __builtin_bit_cast(bf16x8, *(const uint32x4*)(lds + off));
            }
            bf16x8 bfr[3];
#pragma unroll
            for (int g = 0; g < 3; ++g) {
                int dr = wd * 16 + lrow;
                int off = 16384 + g * 4096 + dr * 128 + ((kb * 64 + khalf * 16) ^ ((dr & 7) << 4));
                bfr[g] = __builtin_bit_cast(bf16x8, *(const uint32x4*)(lds + off));
            }
#pragma unroll
            for (int g = 0; g < 3; ++g)
#pragma unroll
                for (int i = 0; i < 4; ++i)
                    acc[g][i] = __builtin_amdgcn_mfma_f32_16x16x32_bf16(af[i], bfr[g], acc[g][i], 0, 0, 0);
        }
    }
    const long bBase = (long)f * 1536;
    {
        int d = d0 + wd * 16 + lrow;
        float bihr = b_ih[bBase + d], bihz = b_ih[bBase + DD + d], bihn = b_ih[bBase + 2 * DD + d];
        float bhr = b_hh[bBase + d], bhz = b_hh[bBase + DD + d], bhn = b_hh[bBase + 2 * DD + d];
#pragma unroll
        for (int i = 0; i < 4; ++i)
#pragma unroll
            for (int q = 0; q < 4; ++q) {
                int row = wm * 64 + i * 16 + khalf * 4 + q;
                float r  = fast_sigmoid(acc[0][i][q] + bihr + bhr);
                float z  = fast_sigmoid(acc[1][i][q] + bihz + bhz);
                float nv = fast_tanh(acc[2][i][q] + bihn + r * bhn);
                out[((long)(n0 + row) * FF + f) * DD + d] = (1.0f - z) * nv;
            }
    }
}

extern "C" void kernel_launch(void* const* d_in, const int* in_sizes, int n_in,
                              void* d_out, int out_size, void* d_ws, size_t ws_size,
                              hipStream_t stream) {
    const float* x   = (const float*)d_in[0];
    const float* W   = (const float*)d_in[1];
    const float* bih = (const float*)d_in[2];
    const float* bhh = (const float*)d_in[3];
    float* out       = (float*)d_out;

    if (ws_size >= (size_t)(XT_BYTES + WT_BYTES)) {
        unsigned char* xT = (unsigned char*)d_ws;
        unsigned char* wT = xT + XT_BYTES;
        prep_x<<<dim3(8192), dim3(256), 0, stream>>>(x, (ushort8*)xT);
        prep_w<<<dim3(4096), dim3(256), 0, stream>>>(W, (ushort8*)wT);
        gru_gemm<<<dim3(4096), dim3(512), 0, stream>>>(xT, wT, bih, bhh, out);
    } else {
        gru_fused_fb<<<dim3(16384), dim3(256), 0, stream>>>(x, W, bih, bhh, out);
    }
}

// Round 6
// 482.715 us; speedup vs baseline: 1.0503x; 1.0503x over previous
//
#include <hip/hip_runtime.h>
#include <stdint.h>

// Problem: N=2048, F=64, S=512, D=512
//   gi[n,f,g] = sum_s x[n,f,s] * W_ih[f,g,s]   (+ b_ih)
//   r=sig(gi_r+b_hr); z=sig(gi_z+b_hz); n=tanh(gi_n + r*b_hn); h=(1-z)*n
//
// R6: 8-phase fine-interleave schedule (T3+T4+T5, m201 template) on the
//     prepassed bf16 images. 256x192 tile, BK=64, 8 waves (2M x 4N d-sliced:
//     each wave owns 16 d-cols x all 3 gates -> epilogue stays wave-local).
//     4 phases per K-tile = (kb, mhalf): {ds_read 7x b128 | stage gload16} ->
//     barrier -> setprio(1) 12 MFMA setprio(0) -> barrier.
//     Double-buffered LDS (112KB), region recycling:
//       A(kt+1) -> other buffer at p0/p1; B(kt+2) -> CURRENT buffer's B region
//       at p3 (B readers finished at p2; phase barriers make it deterministic).
//     Boundary s_waitcnt vmcnt(3): retires tile kt, keeps 3 loads in flight.

#define NN 2048
#define FF 64
#define SS 512
#define DD 512
#define NKT 8

#define A_SLAB 16384   // 128 rows x 64 k x 2B (prepass granularity)
#define B_SLAB 24576   // 3 gates x 64 rows x 64 k x 2B
#define XT_BYTES ((long)64 * 16 * 8 * A_SLAB)   // 134217728
#define WT_BYTES ((long)64 * 8 * 8 * B_SLAB)    // 100663296
#define BUF 57344      // 32KB A (256 rows) + 24KB B (192 rows) per K-tile buf

typedef float f32x4 __attribute__((ext_vector_type(4)));
typedef __bf16 bf16x8 __attribute__((ext_vector_type(8)));
typedef unsigned short ushort8 __attribute__((ext_vector_type(8)));
typedef unsigned int uint32x4 __attribute__((ext_vector_type(4)));

#define AS1 __attribute__((address_space(1)))
#define AS3 __attribute__((address_space(3)))

__device__ __forceinline__ void gload16(const void* gsrc, void* ldst) {
    __builtin_amdgcn_global_load_lds(
        (const AS1 unsigned int*)(uintptr_t)gsrc,
        (AS3 unsigned int*)(unsigned int)(uintptr_t)ldst,
        16, 0, 0);
}

__device__ __forceinline__ ushort8 cvt8(const f32x4 a, const f32x4 b) {
    ushort8 r;
    r[0] = __builtin_bit_cast(unsigned short, (__bf16)a[0]);
    r[1] = __builtin_bit_cast(unsigned short, (__bf16)a[1]);
    r[2] = __builtin_bit_cast(unsigned short, (__bf16)a[2]);
    r[3] = __builtin_bit_cast(unsigned short, (__bf16)a[3]);
    r[4] = __builtin_bit_cast(unsigned short, (__bf16)b[0]);
    r[5] = __builtin_bit_cast(unsigned short, (__bf16)b[1]);
    r[6] = __builtin_bit_cast(unsigned short, (__bf16)b[2]);
    r[7] = __builtin_bit_cast(unsigned short, (__bf16)b[3]);
    return r;
}

__device__ __forceinline__ float fast_sigmoid(float v) {
    return 1.0f / (1.0f + __expf(-v));
}
__device__ __forceinline__ float fast_tanh(float v) {
    return 1.0f - 2.0f / (__expf(2.0f * v) + 1.0f);
}

// ---------------- prepass: x,W -> bf16 LDS-image tiles (unchanged) ----------
extern "C" __global__ __launch_bounds__(256)
void prep_x(const float* __restrict__ x, ushort8* __restrict__ xT) {
    const int b  = blockIdx.x;            // 8192
    const int f  = b >> 7;
    const int mt = (b >> 3) & 15;         // 128-row slab index
    const int kt = b & 7;
    const int t  = threadIdx.x;
    const long slab = (long)b * 1024;
#pragma unroll
    for (int p = 0; p < 4; ++p) {
        int q = p * 256 + t;
        int r = q >> 3;
        int s = (q & 7) ^ (r & 7);
        const f32x4* src = (const f32x4*)(x + ((long)(mt * 128 + r) * FF + f) * SS
                                          + kt * 64 + s * 8);
        xT[slab + q] = cvt8(src[0], src[1]);
    }
}

extern "C" __global__ __launch_bounds__(256)
void prep_w(const float* __restrict__ W, ushort8* __restrict__ wT) {
    const int b  = blockIdx.x;            // 4096
    const int f  = b >> 6;
    const int dt = (b >> 3) & 7;
    const int kt = b & 7;
    const int t  = threadIdx.x;
    const long slab = (long)b * 1536;
#pragma unroll
    for (int p = 0; p < 6; ++p) {
        int q  = p * 256 + t;
        int g  = q >> 9;
        int rr = (q >> 3) & 63;
        int s  = (q & 7) ^ (rr & 7);
        const f32x4* src = (const f32x4*)(W + ((long)f * 1536 + g * DD + dt * 64 + rr) * SS
                                          + kt * 64 + s * 8);
        wT[slab + q] = cvt8(src[0], src[1]);
    }
}

// ---------------- main GEMM + fused gates (8-phase schedule) ----------------
extern "C" __global__ __launch_bounds__(512, 2)
void gru_gemm(const unsigned char* __restrict__ xT, const unsigned char* __restrict__ wT,
              const float* __restrict__ b_ih, const float* __restrict__ b_hh,
              float* __restrict__ out)
{
    __shared__ __align__(16) unsigned char lds[2 * BUF];

    const int t     = threadIdx.x;        // 0..511
    const int lane  = t & 63;
    const int wid   = t >> 6;             // 0..7
    const int wm    = wid >> 2;           // 0..1 (128-row band)
    const int wn    = wid & 3;            // 0..3 (16 d-cols, all 3 gates)
    const int lrow  = lane & 15;
    const int khalf = lane >> 4;

    // T1 XCD mapping: each XCD owns 8 consecutive f; d-tile innermost
    const int bid  = blockIdx.x;          // 0..4095
    const int xcd  = bid & 7;
    const int lid  = bid >> 3;            // 0..511
    const int work = xcd * 512 + lid;
    const int f    = work >> 6;           // 0..63
    const int rem  = work & 63;
    const int mt   = rem >> 3;            // 0..7 (256-row tiles)
    const int dt   = rem & 7;             // 0..7
    const int n0   = mt * 256;
    const int d0   = dt * 64;

    const unsigned char* aS0 = xT + (long)((f * 16 + mt * 2) * 8) * A_SLAB;
    const unsigned char* aS1 = xT + (long)((f * 16 + mt * 2 + 1) * 8) * A_SLAB;
    const unsigned char* bS  = wT + (long)((f * 8 + dt) * 8) * B_SLAB;

    f32x4 acc[3][8];
#pragma unroll
    for (int g = 0; g < 3; ++g)
#pragma unroll
        for (int m = 0; m < 8; ++m)
            acc[g][m] = (f32x4){0.f, 0.f, 0.f, 0.f};

    // ---- prologue: A(0)[4], B(0)[3], B(1)[3]  (order matters for vmcnt) ----
    {
        gload16(aS0 + (0 * 512 + t) * 16, lds + (0 * 512 + t) * 16);
        gload16(aS0 + (1 * 512 + t) * 16, lds + (1 * 512 + t) * 16);
        gload16(aS1 + (0 * 512 + t) * 16, lds + 16384 + (0 * 512 + t) * 16);
        gload16(aS1 + (1 * 512 + t) * 16, lds + 16384 + (1 * 512 + t) * 16);
#pragma unroll
        for (int l = 0; l < 3; ++l)
            gload16(bS + (l * 512 + t) * 16, lds + 32768 + (l * 512 + t) * 16);
#pragma unroll
        for (int l = 0; l < 3; ++l)
            gload16(bS + (long)B_SLAB + (l * 512 + t) * 16,
                    lds + BUF + 32768 + (l * 512 + t) * 16);
    }

#define LDA(DST, BUFP, KB, MH)                                                 \
    _Pragma("unroll")                                                          \
    for (int i = 0; i < 4; ++i) {                                              \
        int row = wm * 128 + (MH) * 64 + i * 16 + lrow;                        \
        int off = row * 128 + (((KB) * 64 + khalf * 16) ^ ((row & 7) << 4));   \
        DST[i] = __builtin_bit_cast(bf16x8, *(const uint32x4*)((BUFP) + off)); \
    }

#define LDB(DST, BUFP, KB)                                                     \
    _Pragma("unroll")                                                          \
    for (int g = 0; g < 3; ++g) {                                              \
        int dr  = wn * 16 + lrow;                                              \
        int off = 32768 + g * 8192 + dr * 128 +                                \
                  (((KB) * 64 + khalf * 16) ^ ((dr & 7) << 4));                \
        DST[g] = __builtin_bit_cast(bf16x8, *(const uint32x4*)((BUFP) + off)); \
    }

#define MM(AV, BV, MH)                                                         \
    __builtin_amdgcn_s_setprio(1);                                             \
    _Pragma("unroll")                                                          \
    for (int g = 0; g < 3; ++g)                                                \
        _Pragma("unroll")                                                      \
        for (int i = 0; i < 4; ++i)                                            \
            acc[g][(MH) * 4 + i] = __builtin_amdgcn_mfma_f32_16x16x32_bf16(    \
                AV[i], BV[g], acc[g][(MH) * 4 + i], 0, 0, 0);                  \
    __builtin_amdgcn_s_setprio(0);

#define BAR() __builtin_amdgcn_s_barrier()

#pragma unroll
    for (int kt = 0; kt < NKT; ++kt) {
        const unsigned char* bufC = lds + (kt & 1) * BUF;       // read buffer
        unsigned char*       bufN = lds + ((kt & 1) ^ 1) * BUF; // A(kt+1) dest
        unsigned char*       bufW = lds + (kt & 1) * BUF;       // B(kt+2) dest
        const int a1 = (kt + 1 < NKT) ? kt + 1 : NKT - 1;       // clamp keeps
        const int b2 = (kt + 2 < NKT) ? kt + 2 : NKT - 1;       // vmcnt uniform

        // ---- boundary: tile kt fully landed for ALL waves ----
        asm volatile("s_waitcnt vmcnt(3)" ::: "memory");
        BAR();

        bf16x8 av[4], bv0[3], bv1[3];

        // p0: kb0, mhalf0  | stage A(kt+1) slab0
        LDB(bv0, bufC, 0);
        LDA(av, bufC, 0, 0);
        gload16(aS0 + (long)a1 * A_SLAB + (0 * 512 + t) * 16,
                bufN + (0 * 512 + t) * 16);
        gload16(aS0 + (long)a1 * A_SLAB + (1 * 512 + t) * 16,
                bufN + (1 * 512 + t) * 16);
        BAR();
        MM(av, bv0, 0);
        BAR();

        // p1: kb0, mhalf1  | stage A(kt+1) slab1
        LDA(av, bufC, 0, 1);
        gload16(aS1 + (long)a1 * A_SLAB + (0 * 512 + t) * 16,
                bufN + 16384 + (0 * 512 + t) * 16);
        gload16(aS1 + (long)a1 * A_SLAB + (1 * 512 + t) * 16,
                bufN + 16384 + (1 * 512 + t) * 16);
        BAR();
        MM(av, bv0, 1);
        BAR();

        // p2: kb1, mhalf0
        LDB(bv1, bufC, 1);
        LDA(av, bufC, 1, 0);
        BAR();
        MM(av, bv1, 0);
        BAR();

        // p3: kb1, mhalf1  | stage B(kt+2) into CURRENT buffer's B region
        //     (B readers finished at p2's closing barrier)
        LDA(av, bufC, 1, 1);
#pragma unroll
        for (int l = 0; l < 3; ++l)
            gload16(bS + (long)b2 * B_SLAB + (l * 512 + t) * 16,
                    bufW + 32768 + (l * 512 + t) * 16);
        BAR();
        MM(av, bv1, 1);
        BAR();
    }
    asm volatile("s_waitcnt vmcnt(0)" ::: "memory");  // drain tail stages

    // ---- fused gate epilogue (wave-local: 128 rows x 16 d, all 3 gates) ----
    const long bBase = (long)f * (3 * DD);
    {
        int d = d0 + wn * 16 + lrow;
        float bihr = b_ih[bBase + d];
        float bihz = b_ih[bBase + DD + d];
        float bihn = b_ih[bBase + 2 * DD + d];
        float bhr  = b_hh[bBase + d];
        float bhz  = b_hh[bBase + DD + d];
        float bhn  = b_hh[bBase + 2 * DD + d];
#pragma unroll
        for (int m = 0; m < 8; ++m) {
#pragma unroll
            for (int q = 0; q < 4; ++q) {
                int row = wm * 128 + m * 16 + khalf * 4 + q;
                float gr = acc[0][m][q] + bihr + bhr;
                float gz = acc[1][m][q] + bihz + bhz;
                float gy = acc[2][m][q] + bihn;
                float r  = fast_sigmoid(gr);
                float z  = fast_sigmoid(gz);
                float nv = fast_tanh(gy + r * bhn);
                long oi  = ((long)(n0 + row) * FF + f) * DD + d;
                out[oi]  = (1.0f - z) * nv;
            }
        }
    }
#undef LDA
#undef LDB
#undef MM
#undef BAR
}

// ---------------- fallback (R3 kernel) if ws too small ----------------
extern "C" __global__ __launch_bounds__(256, 3)
void gru_fused_fb(const float* __restrict__ x, const float* __restrict__ W,
                  const float* __restrict__ b_ih, const float* __restrict__ b_hh,
                  float* __restrict__ out)
{
    __shared__ __align__(16) unsigned char lds[28672];
    const int t     = threadIdx.x;
    const int lane  = t & 63;
    const int wid   = t >> 6;
    const int wm    = wid >> 1;
    const int wd    = wid & 1;
    const int lrow  = lane & 15;
    const int khalf = lane >> 4;
    const int bid  = blockIdx.x;
    const int xcd  = bid & 7;
    const int lid  = bid >> 3;
    const int work = xcd * 2048 + lid;
    const int f    = work >> 8;
    const int rem  = work & 255;
    const int n0   = (rem >> 4) * 128;
    const int d0   = (rem & 15) * 32;
    const int colSeg = t & 7;
    const int rBase  = t >> 3;
    const float* aPtr[4]; int aOff[4];
#pragma unroll
    for (int p = 0; p < 4; ++p) {
        int row = rBase + 32 * p;
        aPtr[p] = x + ((long)(n0 + row) * FF + f) * SS + colSeg * 8;
        aOff[p] = row * 128 + ((colSeg * 16) ^ ((row & 7) << 4));
    }
    const float* bPtr[3]; int bOff[3];
#pragma unroll
    for (int p = 0; p < 3; ++p) {
        int ra = rBase + 32 * p;
        int gate = ra >> 5, dr = ra & 31;
        bPtr[p] = W + ((long)f * 1536 + gate * DD + d0 + dr) * SS + colSeg * 8;
        bOff[p] = 16384 + gate * 4096 + dr * 128 + ((colSeg * 16) ^ ((dr & 7) << 4));
    }
    f32x4 acc[3][4];
#pragma unroll
    for (int g = 0; g < 3; ++g)
#pragma unroll
        for (int i = 0; i < 4; ++i) acc[g][i] = (f32x4){0.f, 0.f, 0.f, 0.f};
    f32x4 va[4][2], vb[3][2];
#pragma unroll
    for (int p = 0; p < 4; ++p) { const f32x4* g = (const f32x4*)aPtr[p]; va[p][0] = g[0]; va[p][1] = g[1]; }
#pragma unroll
    for (int p = 0; p < 3; ++p) { const f32x4* g = (const f32x4*)bPtr[p]; vb[p][0] = g[0]; vb[p][1] = g[1]; }
    for (int kt = 0; kt < 8; ++kt) {
        __syncthreads();
#pragma unroll
        for (int p = 0; p < 4; ++p) *(ushort8*)(lds + aOff[p]) = cvt8(va[p][0], va[p][1]);
#pragma unroll
        for (int p = 0; p < 3; ++p) *(ushort8*)(lds + bOff[p]) = cvt8(vb[p][0], vb[p][1]);
        __syncthreads();
        if (kt + 1 < 8) {
            const long koff = (long)(kt + 1) * 64;
#pragma unroll
            for (int p = 0; p < 4; ++p) { const f32x4* g = (const f32x4*)(aPtr[p] + koff); va[p][0] = g[0]; va[p][1] = g[1]; }
#pragma unroll
            for (int p = 0; p < 3; ++p) { const f32x4* g = (const f32x4*)(bPtr[p] + koff); vb[p][0] = g[0]; vb[p][1] = g[1]; }
        }
#pragma unroll
        for (int kb = 0; kb < 2; ++kb) {
            bf16x8 af[4];
#pragma unroll
            for (int i = 0; i < 4; ++i) {
                int row = wm * 64 + i * 16 + lrow;
                int off = row * 128 + ((kb * 64 + khalf * 16) ^ ((row & 7) << 4));
                af[i] = __builtin_bit_cast(bf16x8, *(const uint32x4*)(lds + off));
            }
            bf16x8 bfr[3];
#pragma unroll
            for (int g = 0; g < 3; ++g) {
                int dr = wd * 16 + lrow;
                int off = 16384 + g * 4096 + dr * 128 + ((kb * 64 + khalf * 16) ^ ((dr & 7) << 4));
                bfr[g] = __builtin_bit_cast(bf16x8, *(const uint32x4*)(lds + off));
            }
#pragma unroll
            for (int g = 0; g < 3; ++g)
#pragma unroll
                for (int i = 0; i < 4; ++i)
                    acc[g][i] = __builtin_amdgcn_mfma_f32_16x16x32_bf16(af[i], bfr[g], acc[g][i], 0, 0, 0);
        }
    }
    const long bBase = (long)f * 1536;
    {
        int d = d0 + wd * 16 + lrow;
        float bihr = b_ih[bBase + d], bihz = b_ih[bBase + DD + d], bihn = b_ih[bBase + 2 * DD + d];
        float bhr = b_hh[bBase + d], bhz = b_hh[bBase + DD + d], bhn = b_hh[bBase + 2 * DD + d];
#pragma unroll
        for (int i = 0; i < 4; ++i)
#pragma unroll
            for (int q = 0; q < 4; ++q) {
                int row = wm * 64 + i * 16 + khalf * 4 + q;
                float r  = fast_sigmoid(acc[0][i][q] + bihr + bhr);
                float z  = fast_sigmoid(acc[1][i][q] + bihz + bhz);
                float nv = fast_tanh(acc[2][i][q] + bihn + r * bhn);
                out[((long)(n0 + row) * FF + f) * DD + d] = (1.0f - z) * nv;
            }
    }
}

extern "C" void kernel_launch(void* const* d_in, const int* in_sizes, int n_in,
                              void* d_out, int out_size, void* d_ws, size_t ws_size,
                              hipStream_t stream) {
    const float* x   = (const float*)d_in[0];
    const float* W   = (const float*)d_in[1];
    const float* bih = (const float*)d_in[2];
    const float* bhh = (const float*)d_in[3];
    float* out       = (float*)d_out;

    if (ws_size >= (size_t)(XT_BYTES + WT_BYTES)) {
        unsigned char* xT = (unsigned char*)d_ws;
        unsigned char* wT = xT + XT_BYTES;
        prep_x<<<dim3(8192), dim3(256), 0, stream>>>(x, (ushort8*)xT);
        prep_w<<<dim3(4096), dim3(256), 0, stream>>>(W, (ushort8*)wT);
        gru_gemm<<<dim3(4096), dim3(512), 0, stream>>>(xT, wT, bih, bhh, out);
    } else {
        gru_fused_fb<<<dim3(16384), dim3(256), 0, stream>>>(x, W, bih, bhh, out);
    }
}

// Round 7
// 467.626 us; speedup vs baseline: 1.0842x; 1.0323x over previous
//
#include <hip/hip_runtime.h>
#include <stdint.h>

// Problem: N=2048, F=64, S=512, D=512
//   gi[n,f,g] = sum_s x[n,f,s] * W_ih[f,g,s]   (+ b_ih)
//   r=sig(gi_r+b_hr); z=sig(gi_z+b_hz); n=tanh(gi_n + r*b_hn); h=(1-z)*n
//
// R7: R4 geometry (128x192 tile, 4 waves, wave-local gate epilogue) +
//     double-buffered LDS (80KB -> 2 blocks/CU co-resident) +
//     counted vmcnt(6) boundaries (T4: tile kt+1's B loads stay in flight) +
//     2 phases/K-tile: ph0 {16 ds_read (B k0+k1 -> regs, A k0), 24 MFMA},
//     lgkmcnt(0)+s_barrier, ph1 {A k1 reads | stage A(kt+1)->other,
//     B(kt+2)->current.B, 24 MFMA}. Fully unrolled, exact vmcnt per iter.

#define NN 2048
#define FF 64
#define SS 512
#define DD 512
#define NKT 8

#define A_SLAB 16384   // 128 rows x 64 k x 2B
#define B_SLAB 24576   // 3 gates x 64 rows x 64 k x 2B
#define XT_BYTES ((long)64 * 16 * 8 * A_SLAB)   // 134217728
#define WT_BYTES ((long)64 * 8 * 8 * B_SLAB)    // 100663296
#define BUFSZ 40960    // 16KB A + 24KB B per K-tile buffer

typedef float f32x4 __attribute__((ext_vector_type(4)));
typedef __bf16 bf16x8 __attribute__((ext_vector_type(8)));
typedef unsigned short ushort8 __attribute__((ext_vector_type(8)));
typedef unsigned int uint32x4 __attribute__((ext_vector_type(4)));

#define AS1 __attribute__((address_space(1)))
#define AS3 __attribute__((address_space(3)))

__device__ __forceinline__ void gload16(const void* gsrc, void* ldst) {
    __builtin_amdgcn_global_load_lds(
        (const AS1 unsigned int*)(uintptr_t)gsrc,
        (AS3 unsigned int*)(unsigned int)(uintptr_t)ldst,
        16, 0, 0);
}

__device__ __forceinline__ ushort8 cvt8(const f32x4 a, const f32x4 b) {
    ushort8 r;
    r[0] = __builtin_bit_cast(unsigned short, (__bf16)a[0]);
    r[1] = __builtin_bit_cast(unsigned short, (__bf16)a[1]);
    r[2] = __builtin_bit_cast(unsigned short, (__bf16)a[2]);
    r[3] = __builtin_bit_cast(unsigned short, (__bf16)a[3]);
    r[4] = __builtin_bit_cast(unsigned short, (__bf16)b[0]);
    r[5] = __builtin_bit_cast(unsigned short, (__bf16)b[1]);
    r[6] = __builtin_bit_cast(unsigned short, (__bf16)b[2]);
    r[7] = __builtin_bit_cast(unsigned short, (__bf16)b[3]);
    return r;
}

__device__ __forceinline__ float fast_sigmoid(float v) {
    return 1.0f / (1.0f + __expf(-v));
}
__device__ __forceinline__ float fast_tanh(float v) {
    return 1.0f - 2.0f / (__expf(2.0f * v) + 1.0f);
}

// ---------------- prepass: x,W -> bf16 LDS-image tiles (unchanged) ----------
extern "C" __global__ __launch_bounds__(256)
void prep_x(const float* __restrict__ x, ushort8* __restrict__ xT) {
    const int b  = blockIdx.x;            // 8192
    const int f  = b >> 7;
    const int mt = (b >> 3) & 15;         // 128-row slab
    const int kt = b & 7;
    const int t  = threadIdx.x;
    const long slab = (long)b * 1024;
#pragma unroll
    for (int p = 0; p < 4; ++p) {
        int q = p * 256 + t;
        int r = q >> 3;
        int s = (q & 7) ^ (r & 7);
        const f32x4* src = (const f32x4*)(x + ((long)(mt * 128 + r) * FF + f) * SS
                                          + kt * 64 + s * 8);
        xT[slab + q] = cvt8(src[0], src[1]);
    }
}

extern "C" __global__ __launch_bounds__(256)
void prep_w(const float* __restrict__ W, ushort8* __restrict__ wT) {
    const int b  = blockIdx.x;            // 4096
    const int f  = b >> 6;
    const int dt = (b >> 3) & 7;
    const int kt = b & 7;
    const int t  = threadIdx.x;
    const long slab = (long)b * 1536;
#pragma unroll
    for (int p = 0; p < 6; ++p) {
        int q  = p * 256 + t;
        int g  = q >> 9;
        int rr = (q >> 3) & 63;
        int s  = (q & 7) ^ (rr & 7);
        const f32x4* src = (const f32x4*)(W + ((long)f * 1536 + g * DD + dt * 64 + rr) * SS
                                          + kt * 64 + s * 8);
        wT[slab + q] = cvt8(src[0], src[1]);
    }
}

// ---------------- main GEMM + fused gates (dbuf + counted vmcnt) ------------
extern "C" __global__ __launch_bounds__(256, 2)
void gru_gemm(const unsigned char* __restrict__ xT, const unsigned char* __restrict__ wT,
              const float* __restrict__ b_ih, const float* __restrict__ b_hh,
              float* __restrict__ out)
{
    // 2 x (A [128][64]bf16 = 16KB @0, B [3][64][64]bf16 = 24KB @16384) = 80KB
    __shared__ __align__(16) unsigned char lds[2 * BUFSZ];

    const int t     = threadIdx.x;        // 0..255
    const int lane  = t & 63;
    const int wid   = t >> 6;             // 0..3
    const int wm    = wid >> 1;           // 0..1 (64-row band)
    const int wd    = wid & 1;            // 0..1 (32 d-cols, all 3 gates)
    const int lrow  = lane & 15;
    const int khalf = lane >> 4;

    // T1 XCD mapping: each XCD owns 8 consecutive f; d-tile innermost
    const int bid  = blockIdx.x;          // 0..8191
    const int xcd  = bid & 7;
    const int lid  = bid >> 3;
    const int work = xcd * 1024 + lid;
    const int f    = work >> 7;           // 0..63
    const int rem  = work & 127;
    const int mt   = rem >> 3;            // 0..15 (128-row tiles)
    const int dt   = rem & 7;             // 0..7
    const int n0   = mt * 128;
    const int d0   = dt * 64;

    const unsigned char* aSlab = xT + (long)((f * 16 + mt) * 8) * A_SLAB;
    const unsigned char* bSlab = wT + (long)((f * 8 + dt) * 8) * B_SLAB;
    const int ldsW = (t & 192) * 16;      // wid*1024 (wave-uniform)

    f32x4 acc[3][4][2];
#pragma unroll
    for (int g = 0; g < 3; ++g)
#pragma unroll
        for (int i = 0; i < 4; ++i)
#pragma unroll
            for (int j = 0; j < 2; ++j)
                acc[g][i][j] = (f32x4){0.f, 0.f, 0.f, 0.f};

    // ---- prologue: A(0)->buf0.A, B(0)->buf0.B, B(1)->buf1.B (FIFO order) ---
#pragma unroll
    for (int p = 0; p < 4; ++p)
        gload16(aSlab + (p * 256 + t) * 16, lds + p * 4096 + ldsW);
#pragma unroll
    for (int p = 0; p < 6; ++p)
        gload16(bSlab + (p * 256 + t) * 16, lds + 16384 + p * 4096 + ldsW);
#pragma unroll
    for (int p = 0; p < 6; ++p)
        gload16(bSlab + (long)B_SLAB + (p * 256 + t) * 16,
                lds + BUFSZ + 16384 + p * 4096 + ldsW);

#define LDA(DST, BUFP, KB)                                                     \
    _Pragma("unroll")                                                          \
    for (int i = 0; i < 4; ++i) {                                              \
        int row = wm * 64 + i * 16 + lrow;                                     \
        int off = row * 128 + (((KB) * 64 + khalf * 16) ^ ((row & 7) << 4));   \
        DST[i] = __builtin_bit_cast(bf16x8, *(const uint32x4*)((BUFP) + off)); \
    }

#define LDB(DST, BUFP, KB)                                                     \
    _Pragma("unroll")                                                          \
    for (int g = 0; g < 3; ++g)                                                \
        _Pragma("unroll")                                                      \
        for (int j = 0; j < 2; ++j) {                                          \
            int dr  = wd * 32 + j * 16 + lrow;                                 \
            int off = 16384 + g * 8192 + dr * 128 +                            \
                      (((KB) * 64 + khalf * 16) ^ ((dr & 7) << 4));            \
            DST[g][j] = __builtin_bit_cast(bf16x8,                             \
                            *(const uint32x4*)((BUFP) + off));                 \
        }

#define MM(AV, BV)                                                             \
    __builtin_amdgcn_s_setprio(1);                                             \
    _Pragma("unroll")                                                          \
    for (int g = 0; g < 3; ++g)                                                \
        _Pragma("unroll")                                                      \
        for (int i = 0; i < 4; ++i)                                            \
            _Pragma("unroll")                                                  \
            for (int j = 0; j < 2; ++j)                                        \
                acc[g][i][j] = __builtin_amdgcn_mfma_f32_16x16x32_bf16(        \
                    AV[i], BV[g][j], acc[g][i][j], 0, 0, 0);                   \
    __builtin_amdgcn_s_setprio(0);

    // One K-tile iteration. Boundary: vmcnt(VM) retires tile KT's loads,
    // keeps B(KT+1)'s 6 in flight. ph0 reads ALL B (k0+k1) + A(k0) -> 24 MFMA.
    // lgkmcnt(0)+barrier => every wave's ph0 reads are COMPLETE chip-wide,
    // so ph1 may overwrite current.B with B(KT+2) while computing k1.
#define ITER(KT, VM, DO_A, DO_B)                                               \
    {                                                                          \
        asm volatile("s_waitcnt vmcnt(" #VM ")" ::: "memory");                 \
        __builtin_amdgcn_s_barrier();                                          \
        asm volatile("" ::: "memory");                                         \
        const unsigned char* bufC = lds + ((KT) & 1) * BUFSZ;                  \
        unsigned char* bufO = lds + (((KT) & 1) ^ 1) * BUFSZ;                  \
        bf16x8 av[4], bv0[3][2], bv1[3][2];                                    \
        LDB(bv0, bufC, 0);                                                     \
        LDB(bv1, bufC, 1);                                                     \
        LDA(av, bufC, 0);                                                      \
        MM(av, bv0);                                                           \
        asm volatile("s_waitcnt lgkmcnt(0)" ::: "memory");                     \
        __builtin_amdgcn_s_barrier();                                          \
        asm volatile("" ::: "memory");                                         \
        LDA(av, bufC, 1);                                                      \
        if (DO_A) {                                                            \
            _Pragma("unroll")                                                  \
            for (int p = 0; p < 4; ++p)                                        \
                gload16(aSlab + (long)((KT) + 1) * A_SLAB + (p * 256 + t) * 16,\
                        bufO + p * 4096 + ldsW);                               \
        }                                                                      \
        if (DO_B) {                                                            \
            _Pragma("unroll")                                                  \
            for (int p = 0; p < 6; ++p)                                        \
                gload16(bSlab + (long)((KT) + 2) * B_SLAB + (p * 256 + t) * 16,\
                        (unsigned char*)bufC + 16384 + p * 4096 + ldsW);       \
        }                                                                      \
        MM(av, bv1);                                                           \
    }

    ITER(0, 6, 1, 1)
    ITER(1, 6, 1, 1)
    ITER(2, 6, 1, 1)
    ITER(3, 6, 1, 1)
    ITER(4, 6, 1, 1)
    ITER(5, 6, 1, 1)
    ITER(6, 6, 1, 0)   // stage A(7) only; B(8) doesn't exist
    ITER(7, 0, 0, 0)   // final tile: drain everything, no staging

    // ---- fused gate epilogue (wave-local: 64 rows x 32 d, all 3 gates) -----
    const long bBase = (long)f * (3 * DD);
#pragma unroll
    for (int j = 0; j < 2; ++j) {
        int d = d0 + wd * 32 + j * 16 + lrow;
        float bihr = b_ih[bBase + d];
        float bihz = b_ih[bBase + DD + d];
        float bihn = b_ih[bBase + 2 * DD + d];
        float bhr  = b_hh[bBase + d];
        float bhz  = b_hh[bBase + DD + d];
        float bhn  = b_hh[bBase + 2 * DD + d];
#pragma unroll
        for (int i = 0; i < 4; ++i) {
#pragma unroll
            for (int q = 0; q < 4; ++q) {
                int row = wm * 64 + i * 16 + khalf * 4 + q;
                float gr = acc[0][i][j][q] + bihr + bhr;
                float gz = acc[1][i][j][q] + bihz + bhz;
                float gy = acc[2][i][j][q] + bihn;
                float r  = fast_sigmoid(gr);
                float z  = fast_sigmoid(gz);
                float nv = fast_tanh(gy + r * bhn);
                long oi  = ((long)(n0 + row) * FF + f) * DD + d;
                out[oi]  = (1.0f - z) * nv;
            }
        }
    }
#undef LDA
#undef LDB
#undef MM
#undef ITER
}

// ---------------- fallback (R3 kernel) if ws too small ----------------
extern "C" __global__ __launch_bounds__(256, 3)
void gru_fused_fb(const float* __restrict__ x, const float* __restrict__ W,
                  const float* __restrict__ b_ih, const float* __restrict__ b_hh,
                  float* __restrict__ out)
{
    __shared__ __align__(16) unsigned char lds[28672];
    const int t     = threadIdx.x;
    const int lane  = t & 63;
    const int wid   = t >> 6;
    const int wm    = wid >> 1;
    const int wd    = wid & 1;
    const int lrow  = lane & 15;
    const int khalf = lane >> 4;
    const int bid  = blockIdx.x;
    const int xcd  = bid & 7;
    const int lid  = bid >> 3;
    const int work = xcd * 2048 + lid;
    const int f    = work >> 8;
    const int rem  = work & 255;
    const int n0   = (rem >> 4) * 128;
    const int d0   = (rem & 15) * 32;
    const int colSeg = t & 7;
    const int rBase  = t >> 3;
    const float* aPtr[4]; int aOff[4];
#pragma unroll
    for (int p = 0; p < 4; ++p) {
        int row = rBase + 32 * p;
        aPtr[p] = x + ((long)(n0 + row) * FF + f) * SS + colSeg * 8;
        aOff[p] = row * 128 + ((colSeg * 16) ^ ((row & 7) << 4));
    }
    const float* bPtr[3]; int bOff[3];
#pragma unroll
    for (int p = 0; p < 3; ++p) {
        int ra = rBase + 32 * p;
        int gate = ra >> 5, dr = ra & 31;
        bPtr[p] = W + ((long)f * 1536 + gate * DD + d0 + dr) * SS + colSeg * 8;
        bOff[p] = 16384 + gate * 4096 + dr * 128 + ((colSeg * 16) ^ ((dr & 7) << 4));
    }
    f32x4 acc[3][4];
#pragma unroll
    for (int g = 0; g < 3; ++g)
#pragma unroll
        for (int i = 0; i < 4; ++i) acc[g][i] = (f32x4){0.f, 0.f, 0.f, 0.f};
    f32x4 va[4][2], vb[3][2];
#pragma unroll
    for (int p = 0; p < 4; ++p) { const f32x4* g = (const f32x4*)aPtr[p]; va[p][0] = g[0]; va[p][1] = g[1]; }
#pragma unroll
    for (int p = 0; p < 3; ++p) { const f32x4* g = (const f32x4*)bPtr[p]; vb[p][0] = g[0]; vb[p][1] = g[1]; }
    for (int kt = 0; kt < 8; ++kt) {
        __syncthreads();
#pragma unroll
        for (int p = 0; p < 4; ++p) *(ushort8*)(lds + aOff[p]) = cvt8(va[p][0], va[p][1]);
#pragma unroll
        for (int p = 0; p < 3; ++p) *(ushort8*)(lds + bOff[p]) = cvt8(vb[p][0], vb[p][1]);
        __syncthreads();
        if (kt + 1 < 8) {
            const long koff = (long)(kt + 1) * 64;
#pragma unroll
            for (int p = 0; p < 4; ++p) { const f32x4* g = (const f32x4*)(aPtr[p] + koff); va[p][0] = g[0]; va[p][1] = g[1]; }
#pragma unroll
            for (int p = 0; p < 3; ++p) { const f32x4* g = (const f32x4*)(bPtr[p] + koff); vb[p][0] = g[0]; vb[p][1] = g[1]; }
        }
#pragma unroll
        for (int kb = 0; kb < 2; ++kb) {
            bf16x8 af[4];
#pragma unroll
            for (int i = 0; i < 4; ++i) {
                int row = wm * 64 + i * 16 + lrow;
                int off = row * 128 + ((kb * 64 + khalf * 16) ^ ((row & 7) << 4));
                af[i] = __builtin_bit_cast(bf16x8, *(const uint32x4*)(lds + off));
            }
            bf16x8 bfr[3];
#pragma unroll
            for (int g = 0; g < 3; ++g) {
                int dr = wd * 16 + lrow;
                int off = 16384 + g * 4096 + dr * 128 + ((kb * 64 + khalf * 16) ^ ((dr & 7) << 4));
                bfr[g] = __builtin_bit_cast(bf16x8, *(const uint32x4*)(lds + off));
            }
#pragma unroll
            for (int g = 0; g < 3; ++g)
#pragma unroll
                for (int i = 0; i < 4; ++i)
                    acc[g][i] = __builtin_amdgcn_mfma_f32_16x16x32_bf16(af[i], bfr[g], acc[g][i], 0, 0, 0);
        }
    }
    const long bBase = (long)f * 1536;
    {
        int d = d0 + wd * 16 + lrow;
        float bihr = b_ih[bBase + d], bihz = b_ih[bBase + DD + d], bihn = b_ih[bBase + 2 * DD + d];
        float bhr = b_hh[bBase + d], bhz = b_hh[bBase + DD + d], bhn = b_hh[bBase + 2 * DD + d];
#pragma unroll
        for (int i = 0; i < 4; ++i)
#pragma unroll
            for (int q = 0; q < 4; ++q) {
                int row = wm * 64 + i * 16 + khalf * 4 + q;
                float r  = fast_sigmoid(acc[0][i][q] + bihr + bhr);
                float z  = fast_sigmoid(acc[1][i][q] + bihz + bhz);
                float nv = fast_tanh(acc[2][i][q] + bihn + r * bhn);
                out[((long)(n0 + row) * FF + f) * DD + d] = (1.0f - z) * nv;
            }
    }
}

extern "C" void kernel_launch(void* const* d_in, const int* in_sizes, int n_in,
                              void* d_out, int out_size, void* d_ws, size_t ws_size,
                              hipStream_t stream) {
    const float* x   = (const float*)d_in[0];
    const float* W   = (const float*)d_in[1];
    const float* bih = (const float*)d_in[2];
    const float* bhh = (const float*)d_in[3];
    float* out       = (float*)d_out;

    if (ws_size >= (size_t)(XT_BYTES + WT_BYTES)) {
        unsigned char* xT = (unsigned char*)d_ws;
        unsigned char* wT = xT + XT_BYTES;
        prep_x<<<dim3(8192), dim3(256), 0, stream>>>(x, (ushort8*)xT);
        prep_w<<<dim3(4096), dim3(256), 0, stream>>>(W, (ushort8*)wT);
        gru_gemm<<<dim3(8192), dim3(256), 0, stream>>>(xT, wT, bih, bhh, out);
    } else {
        gru_fused_fb<<<dim3(16384), dim3(256), 0, stream>>>(x, W, bih, bhh, out);
    }
}